// Round 2
// baseline (5744.469 us; speedup 1.0000x reference)
//
#include <hip/hip_runtime.h>
#include <hip/hip_fp16.h>

#define B_ 8
#define H_ 16
#define L_ 1024
#define DH_ 64
#define DM_ 1024
#define NP_ 2047
#define NP2_ 2048
#define SCALE_ 0.125f

// ---------------- projection GEMM: Y = X @ W^T ----------------
// X: (M,1024) row-major, W: (1024 out, 1024 in) row-major (torch Linear).
// MODE 0: Y[((b*H + h)*L + l)*64 + dh]  head-split layout (h == blockIdx.y)
// MODE 1: Y[row*1024 + e]               flat layout
template <int MODE>
__global__ __launch_bounds__(256) void proj_gemm(const float* __restrict__ X,
                                                 const float* __restrict__ W,
                                                 float* __restrict__ Y)
{
    __shared__ __align__(16) float As[16][68];
    __shared__ __align__(16) float Bs[16][68];
    const int t   = threadIdx.x;
    const int tm  = t & 15;        // micro row
    const int tn  = t >> 4;        // micro col
    const int row0 = blockIdx.x * 64;
    const int col0 = blockIdx.y * 64;
    const int lr = t >> 2;         // staging row 0..63
    const int lc = (t & 3) * 4;    // staging col 0,4,8,12

    float acc[4][4];
#pragma unroll
    for (int i = 0; i < 4; ++i)
#pragma unroll
        for (int j = 0; j < 4; ++j) acc[i][j] = 0.f;

    for (int k0 = 0; k0 < DM_; k0 += 16) {
        float4 av = *(const float4*)(X + (size_t)(row0 + lr) * DM_ + k0 + lc);
        float4 wv = *(const float4*)(W + (size_t)(col0 + lr) * DM_ + k0 + lc);
        __syncthreads();   // previous tile fully consumed
        As[lc + 0][lr] = av.x; As[lc + 1][lr] = av.y;
        As[lc + 2][lr] = av.z; As[lc + 3][lr] = av.w;
        Bs[lc + 0][lr] = wv.x; Bs[lc + 1][lr] = wv.y;
        Bs[lc + 2][lr] = wv.z; Bs[lc + 3][lr] = wv.w;
        __syncthreads();
#pragma unroll
        for (int kk = 0; kk < 16; ++kk) {
            float4 a  = *(const float4*)&As[kk][tm * 4];
            float4 w4 = *(const float4*)&Bs[kk][tn * 4];
            acc[0][0] = fmaf(a.x, w4.x, acc[0][0]);
            acc[0][1] = fmaf(a.x, w4.y, acc[0][1]);
            acc[0][2] = fmaf(a.x, w4.z, acc[0][2]);
            acc[0][3] = fmaf(a.x, w4.w, acc[0][3]);
            acc[1][0] = fmaf(a.y, w4.x, acc[1][0]);
            acc[1][1] = fmaf(a.y, w4.y, acc[1][1]);
            acc[1][2] = fmaf(a.y, w4.z, acc[1][2]);
            acc[1][3] = fmaf(a.y, w4.w, acc[1][3]);
            acc[2][0] = fmaf(a.z, w4.x, acc[2][0]);
            acc[2][1] = fmaf(a.z, w4.y, acc[2][1]);
            acc[2][2] = fmaf(a.z, w4.z, acc[2][2]);
            acc[2][3] = fmaf(a.z, w4.w, acc[2][3]);
            acc[3][0] = fmaf(a.w, w4.x, acc[3][0]);
            acc[3][1] = fmaf(a.w, w4.y, acc[3][1]);
            acc[3][2] = fmaf(a.w, w4.z, acc[3][2]);
            acc[3][3] = fmaf(a.w, w4.w, acc[3][3]);
        }
    }

#pragma unroll
    for (int i = 0; i < 4; ++i) {
        const int row = row0 + tm * 4 + i;
        float4 r = make_float4(acc[i][0], acc[i][1], acc[i][2], acc[i][3]);
        if (MODE == 0) {
            const int bb = row >> 10;
            const int l  = row & 1023;
            *(float4*)(Y + (((size_t)bb * H_ + blockIdx.y) * L_ + l) * DH_ + tn * 4) = r;
        } else {
            *(float4*)(Y + (size_t)row * DM_ + col0 + tn * 4) = r;
        }
    }
}

// ---------------- Shaw relative attention, 8 query rows per block ----------------
// grid (L/8, H, B), 512 threads = 8 waves. Wave-sliced tiles: for each staged
// 64-row tile, wave w consumes ONLY rows w*8..w*8+7 (8x less LDS read traffic
// than all-waves-read-all-rows). Phases:
//   A: load q rows, zero hist
//   B: qrel[r][p] = q_r . rel_k[p] for all p (wave-sliced over p)
//   C: S[r][j] = (q_r.k_j + qrel[r][idx[r][j]]) * scale (wave-sliced over j)
//   D: row softmax (wave w owns row w); S holds UNNORMALIZED probs
//   E: partial O[r] += S[r][j] * V[j]      (wave-sliced over j, partials in regs)
//   F: hist[w][p] += S[w][j] (idx[w][j]==p), LDS f32 atomics
//   G: partial O[r] += hist[r][p] * rel_v[p] (wave-sliced over p)
//   H: cross-wave reduce partials (aliased into dead qrel buffer), normalize, store
__global__ __launch_bounds__(512) void shaw_attn_kernel(
    const float* __restrict__ q, const float* __restrict__ k,
    const float* __restrict__ v, const int* __restrict__ ridx,
    const float* __restrict__ rel_k, const float* __restrict__ rel_v,
    float* __restrict__ out)
{
    __shared__ __align__(16) float qs[8][68];                          //  2.1 KB
    __shared__ __align__(16) unsigned char qrel_red_raw[8 * NP2_ * 2]; // 32 KB (qrel half / red float)
    __shared__ __align__(16) float S[8][L_];                           // 32 KB
    __shared__ __align__(16) float hist[8][NP2_];                      // 64 KB
    __shared__ __align__(16) float stage[64][68];                      // 17.4 KB
    // total ~147 KB -> 1 block/CU

    __half (*qrel)[NP2_] = (__half (*)[NP2_])qrel_red_raw;
    float* red = (float*)qrel_red_raw;   // [8 waves][8 rows][68] after qrel is dead

    const int t    = threadIdx.x;
    const int w    = t >> 6;        // wave id
    const int lane = t & 63;
    const int i0   = blockIdx.x * 8;
    const int h    = blockIdx.y;
    const int b    = blockIdx.z;
    const size_t bh = (size_t)b * H_ + h;
    const float* qp = q + bh * (size_t)(L_ * DH_);
    const float* kp = k + bh * (size_t)(L_ * DH_);
    const float* vp = v + bh * (size_t)(L_ * DH_);

    const int sr = t >> 3;          // staging row 0..63
    const int sc = (t & 7) * 8;     // staging col 0,8,...,56

    const int ti   = lane & 7;       // query row for phases B/C (8 lanes share a row)
    const int prow = w * 8 + (lane >> 3);   // this thread's stage row in B/C

    // ---- Phase A ----
    qs[w][lane] = qp[(size_t)(i0 + w) * DH_ + lane];
    for (int r = t; r < 8 * NP2_; r += 512) (&hist[0][0])[r] = 0.f;
    __syncthreads();

    float qreg[64];
#pragma unroll
    for (int d = 0; d < 64; ++d) qreg[d] = qs[ti][d];

    // register double-buffered staging
    float4 u0, u1;
    auto prefetch = [&](const float* __restrict__ src, int row_limit, int c) {
        const int rr = c * 64 + sr;
        u0 = make_float4(0.f, 0.f, 0.f, 0.f); u1 = u0;
        if (rr < row_limit) {
            u0 = *(const float4*)(src + (size_t)rr * DH_ + sc);
            u1 = *(const float4*)(src + (size_t)rr * DH_ + sc + 4);
        }
    };
    auto commit = [&]() {
        *(float4*)&stage[sr][sc]     = u0;
        *(float4*)&stage[sr][sc + 4] = u1;
    };
    // dot(q_ti, stage[prow])  — 8-way broadcast groups, conflict-free banks
    auto dotq = [&]() -> float {
        const float4* sp = (const float4*)&stage[prow][0];
        float a0 = 0.f, a1 = 0.f, a2 = 0.f, a3 = 0.f;
#pragma unroll
        for (int d4 = 0; d4 < 16; ++d4) {
            float4 s4 = sp[d4];
            a0 = fmaf(s4.x, qreg[d4 * 4 + 0], a0);
            a1 = fmaf(s4.y, qreg[d4 * 4 + 1], a1);
            a2 = fmaf(s4.z, qreg[d4 * 4 + 2], a2);
            a3 = fmaf(s4.w, qreg[d4 * 4 + 3], a3);
        }
        return (a0 + a1) + (a2 + a3);
    };

    // ---- Phase B: qrel[ti][p] for all p ----
    prefetch(rel_k, NP_, 0);
    for (int c = 0; c < 32; ++c) {
        __syncthreads();                    // previous tile consumers done
        commit();
        __syncthreads();                    // stage ready
        if (c + 1 < 32) prefetch(rel_k, NP_, c + 1);   // hide L2 latency under compute
        qrel[ti][c * 64 + prow] = __float2half(dotq());
    }

    // ---- Phase C: scores ----
    const int* idxr = ridx + (size_t)(i0 + ti) * L_;
    prefetch(kp, L_, 0);
    for (int c = 0; c < 16; ++c) {
        __syncthreads();
        commit();
        __syncthreads();
        if (c + 1 < 16) prefetch(kp, L_, c + 1);
        const int j = c * 64 + prow;
        const float content = dotq();
        const float relv = __half2float(qrel[ti][idxr[j]]);
        S[ti][j] = (content + relv) * SCALE_;
    }
    __syncthreads();   // S complete (cross-wave) before softmax reads

    // ---- Phase D: softmax, wave w owns row w; probs left UNNORMALIZED ----
    float m = -1e30f;
#pragma unroll
    for (int c2 = 0; c2 < 16; ++c2) m = fmaxf(m, S[w][c2 * 64 + lane]);
#pragma unroll
    for (int off = 32; off >= 1; off >>= 1) m = fmaxf(m, __shfl_xor(m, off));
    float sum = 0.f;
#pragma unroll
    for (int c2 = 0; c2 < 16; ++c2) {
        const float e = __expf(S[w][c2 * 64 + lane] - m);
        S[w][c2 * 64 + lane] = e;
        sum += e;
    }
#pragma unroll
    for (int off = 32; off >= 1; off >>= 1) sum += __shfl_xor(sum, off);
    const float inv_l = 1.0f / sum;

    // ---- Phase E: O partials over V (wave-sliced j), all 8 rows per wave ----
    float op[8];
#pragma unroll
    for (int r = 0; r < 8; ++r) op[r] = 0.f;

    prefetch(vp, L_, 0);
    for (int c = 0; c < 16; ++c) {
        __syncthreads();                    // also orders D's S writes before E's S reads
        commit();
        __syncthreads();
        if (c + 1 < 16) prefetch(vp, L_, c + 1);
        float sreg[8];
#pragma unroll
        for (int jj = 0; jj < 8; ++jj) sreg[jj] = stage[w * 8 + jj][lane];
#pragma unroll
        for (int r = 0; r < 8; ++r) {
            const float4 pa = *(const float4*)&S[r][c * 64 + w * 8];
            const float4 pb = *(const float4*)&S[r][c * 64 + w * 8 + 4];
            op[r] = fmaf(pa.x, sreg[0], op[r]);
            op[r] = fmaf(pa.y, sreg[1], op[r]);
            op[r] = fmaf(pa.z, sreg[2], op[r]);
            op[r] = fmaf(pa.w, sreg[3], op[r]);
            op[r] = fmaf(pb.x, sreg[4], op[r]);
            op[r] = fmaf(pb.y, sreg[5], op[r]);
            op[r] = fmaf(pb.z, sreg[6], op[r]);
            op[r] = fmaf(pb.w, sreg[7], op[r]);
        }
    }

    // ---- Phase F: histogram scatter (own row, LDS f32 atomics) ----
    const int* idxw = ridx + (size_t)(i0 + w) * L_;
    for (int c = 0; c < 16; ++c) {
        const int j = c * 64 + lane;
        atomicAdd(&hist[w][idxw[j]], S[w][j]);
    }

    // ---- Phase G: O partials over rel_v (wave-sliced p) ----
    prefetch(rel_v, NP_, 0);
    for (int c = 0; c < 32; ++c) {
        __syncthreads();                    // orders F's atomics before G's hist reads
        commit();
        __syncthreads();
        if (c + 1 < 32) prefetch(rel_v, NP_, c + 1);
        float sreg[8];
#pragma unroll
        for (int jj = 0; jj < 8; ++jj) sreg[jj] = stage[w * 8 + jj][lane];
#pragma unroll
        for (int r = 0; r < 8; ++r) {
            const float4 ha = *(const float4*)&hist[r][c * 64 + w * 8];
            const float4 hb = *(const float4*)&hist[r][c * 64 + w * 8 + 4];
            op[r] = fmaf(ha.x, sreg[0], op[r]);
            op[r] = fmaf(ha.y, sreg[1], op[r]);
            op[r] = fmaf(ha.z, sreg[2], op[r]);
            op[r] = fmaf(ha.w, sreg[3], op[r]);
            op[r] = fmaf(hb.x, sreg[4], op[r]);
            op[r] = fmaf(hb.y, sreg[5], op[r]);
            op[r] = fmaf(hb.z, sreg[6], op[r]);
            op[r] = fmaf(hb.w, sreg[7], op[r]);
        }
    }

    // ---- Phase H: cross-wave reduce + normalize + store ----
    __syncthreads();                        // all G computes done
#pragma unroll
    for (int r = 0; r < 8; ++r) red[(w * 8 + r) * 68 + lane] = op[r];
    __syncthreads();
    float o = 0.f;
#pragma unroll
    for (int wp = 0; wp < 8; ++wp) o += red[(wp * 8 + w) * 68 + lane];
    out[((size_t)b * L_ + i0 + w) * DM_ + h * DH_ + lane] = o * inv_l;
}

extern "C" void kernel_launch(void* const* d_in, const int* in_sizes, int n_in,
                              void* d_out, int out_size, void* d_ws, size_t ws_size,
                              hipStream_t stream)
{
    const float* x    = (const float*)d_in[0];
    const int*   ridx = (const int*)  d_in[1];
    const float* Wq   = (const float*)d_in[2];
    const float* Wk   = (const float*)d_in[3];
    const float* Wv   = (const float*)d_in[4];
    const float* Wo   = (const float*)d_in[5];
    const float* rk   = (const float*)d_in[6];
    const float* rv   = (const float*)d_in[7];
    float* out = (float*)d_out;
    float* ws  = (float*)d_ws;

    const size_t NQ = (size_t)B_ * H_ * L_ * DH_;   // 8.39M elems per buffer
    float* qb   = ws;
    float* kb   = ws + NQ;
    float* vb   = ws + 2 * NQ;
    float* attn = ws + 3 * NQ;

    dim3 gthr(256);
    dim3 ggrid((B_ * L_) / 64, DM_ / 64);   // (128, 16)

    proj_gemm<0><<<ggrid, gthr, 0, stream>>>(x, Wq, qb);
    proj_gemm<0><<<ggrid, gthr, 0, stream>>>(x, Wk, kb);
    proj_gemm<0><<<ggrid, gthr, 0, stream>>>(x, Wv, vb);

    shaw_attn_kernel<<<dim3(L_ / 8, H_, B_), dim3(512), 0, stream>>>(
        qb, kb, vb, ridx, rk, rv, attn);

    proj_gemm<1><<<ggrid, gthr, 0, stream>>>(attn, Wo, out);
}

// Round 3
// 2846.778 us; speedup vs baseline: 2.0179x; 2.0179x over previous
//
#include <hip/hip_runtime.h>

#define B_ 8
#define H_ 16
#define L_ 1024
#define DH_ 64
#define DM_ 1024
#define NP_ 2047
#define NP2_ 2048
#define SCALE_ 0.125f

#define SS_ 1028   // S/hist f32 row stride (pad: conflict-free MFMA C writes)
#define PS_ 1032   // P bf16 row stride (pad: 8-way-min b128 A-frag reads)

typedef __attribute__((ext_vector_type(8))) short bf16x8;
typedef __attribute__((ext_vector_type(4))) float f32x4;

__device__ __forceinline__ unsigned short f2bf(float x) {
    union { float f; unsigned int u; } v; v.f = x;
    return (unsigned short)((v.u + 0x7FFFu + ((v.u >> 16) & 1u)) >> 16);
}
__device__ __forceinline__ float bf2f(unsigned short b) {
    union { unsigned int u; float f; } v; v.u = ((unsigned int)b) << 16;
    return v.f;
}

// ---------------- projection GEMM: Y = X @ W^T (fp32 VALU core) ----------------
// MODE 0: head-split hi/lo bf16: Y0/Y1[((b*H+h)*L + l)*64 + dh]   (q, k)
// MODE 1: fp32 flat: Y0[row*1024 + e]                              (Wo)
// MODE 2: head-split TRANSPOSED bf16: Y0[((b*H+h)*64 + dh)*1024+l] (v)
template <int MODE>
__global__ __launch_bounds__(256) void proj_gemm(const float* __restrict__ X,
                                                 const float* __restrict__ W,
                                                 float* __restrict__ Yf,
                                                 unsigned short* __restrict__ Y0,
                                                 unsigned short* __restrict__ Y1)
{
    __shared__ __align__(16) float As[16][68];
    __shared__ __align__(16) float Bs[16][68];
    const int t   = threadIdx.x;
    const int tm  = t & 15;
    const int tn  = t >> 4;
    const int row0 = blockIdx.x * 64;
    const int col0 = blockIdx.y * 64;
    const int lr = t >> 2;
    const int lc = (t & 3) * 4;

    float acc[4][4];
#pragma unroll
    for (int i = 0; i < 4; ++i)
#pragma unroll
        for (int j = 0; j < 4; ++j) acc[i][j] = 0.f;

    for (int k0 = 0; k0 < DM_; k0 += 16) {
        float4 av = *(const float4*)(X + (size_t)(row0 + lr) * DM_ + k0 + lc);
        float4 wv = *(const float4*)(W + (size_t)(col0 + lr) * DM_ + k0 + lc);
        __syncthreads();
        As[lc + 0][lr] = av.x; As[lc + 1][lr] = av.y;
        As[lc + 2][lr] = av.z; As[lc + 3][lr] = av.w;
        Bs[lc + 0][lr] = wv.x; Bs[lc + 1][lr] = wv.y;
        Bs[lc + 2][lr] = wv.z; Bs[lc + 3][lr] = wv.w;
        __syncthreads();
#pragma unroll
        for (int kk = 0; kk < 16; ++kk) {
            float4 a  = *(const float4*)&As[kk][tm * 4];
            float4 w4 = *(const float4*)&Bs[kk][tn * 4];
            acc[0][0] = fmaf(a.x, w4.x, acc[0][0]);
            acc[0][1] = fmaf(a.x, w4.y, acc[0][1]);
            acc[0][2] = fmaf(a.x, w4.z, acc[0][2]);
            acc[0][3] = fmaf(a.x, w4.w, acc[0][3]);
            acc[1][0] = fmaf(a.y, w4.x, acc[1][0]);
            acc[1][1] = fmaf(a.y, w4.y, acc[1][1]);
            acc[1][2] = fmaf(a.y, w4.z, acc[1][2]);
            acc[1][3] = fmaf(a.y, w4.w, acc[1][3]);
            acc[2][0] = fmaf(a.z, w4.x, acc[2][0]);
            acc[2][1] = fmaf(a.z, w4.y, acc[2][1]);
            acc[2][2] = fmaf(a.z, w4.z, acc[2][2]);
            acc[2][3] = fmaf(a.z, w4.w, acc[2][3]);
            acc[3][0] = fmaf(a.w, w4.x, acc[3][0]);
            acc[3][1] = fmaf(a.w, w4.y, acc[3][1]);
            acc[3][2] = fmaf(a.w, w4.z, acc[3][2]);
            acc[3][3] = fmaf(a.w, w4.w, acc[3][3]);
        }
    }

    const int h = blockIdx.y;   // for MODE 0/2 (col0 = h*64)
#pragma unroll
    for (int i = 0; i < 4; ++i) {
        const int row = row0 + tm * 4 + i;
        if (MODE == 1) {
            float4 r = make_float4(acc[i][0], acc[i][1], acc[i][2], acc[i][3]);
            *(float4*)(Yf + (size_t)row * DM_ + col0 + tn * 4) = r;
        } else {
            const int bb = row >> 10;
            const int l  = row & 1023;
            if (MODE == 0) {
                ushort4 hi4, lo4;
                unsigned short* hp = (unsigned short*)&hi4;
                unsigned short* lp = (unsigned short*)&lo4;
#pragma unroll
                for (int j = 0; j < 4; ++j) {
                    unsigned short hb = f2bf(acc[i][j]);
                    hp[j] = hb;
                    lp[j] = f2bf(acc[i][j] - bf2f(hb));
                }
                const size_t base = (((size_t)bb * H_ + h) * L_ + l) * DH_ + tn * 4;
                *(ushort4*)(Y0 + base) = hi4;
                *(ushort4*)(Y1 + base) = lo4;
            } else {  // MODE 2: transposed bf16
#pragma unroll
                for (int j = 0; j < 4; ++j) {
                    const int d = tn * 4 + j;
                    Y0[(((size_t)bb * H_ + h) * DH_ + d) * L_ + l] = f2bf(acc[i][j]);
                }
            }
        }
    }
}

// ---------------- rel_k split + rel_v transpose prep ----------------
// rk_hi/rk_lo: [2048][64] bf16 (row 2047 zero); rv_t: [64][2048] bf16 (col 2047 zero)
__global__ __launch_bounds__(256) void prep_rel(const float* __restrict__ rk,
                                                const float* __restrict__ rv,
                                                unsigned short* __restrict__ rk_hi,
                                                unsigned short* __restrict__ rk_lo,
                                                unsigned short* __restrict__ rv_t)
{
    const int idx = blockIdx.x * 256 + threadIdx.x;   // 0 .. 2048*64-1
    const int p = idx >> 6;
    const int d = idx & 63;
    float xk = (p < NP_) ? rk[(size_t)p * DH_ + d] : 0.f;
    unsigned short hb = f2bf(xk);
    rk_hi[idx] = hb;
    rk_lo[idx] = f2bf(xk - bf2f(hb));
    float xv = (p < NP_) ? rv[(size_t)p * DH_ + d] : 0.f;
    rv_t[(size_t)d * NP2_ + p] = f2bf(xv);
}

// ---------------- MFMA Shaw attention: 16 Q-rows per block, 8 waves ----------------
// grid (L/16, H, B), 512 threads.
// Phase 1: Qrel[16][2048] = Q @ rel_k^T  (split-bf16, wave-sliced over p-tiles)
// Phase 2: S = (Q @ K^T + Qrel[idx]) * scale  (split-bf16, wave-sliced over j-tiles)
// Phase 3: row softmax (wave w: rows 2w,2w+1) -> P bf16 (unnormalized), inv_l
// Phase 4: O1 partial = P @ V      (wave task (n=w&3, khalf=w>>2))
// Phase 5: 2 passes: hist scatter (LDS f32 atomics) + O2 partial = hist @ rel_v
// Phase 6: cross-wave khalf reduce, normalize, store fp32 head-merged
__global__ __launch_bounds__(512) void shaw_attn_mfma(
    const unsigned short* __restrict__ qh, const unsigned short* __restrict__ ql,
    const unsigned short* __restrict__ kh, const unsigned short* __restrict__ kl,
    const unsigned short* __restrict__ vt, const int* __restrict__ ridx,
    const unsigned short* __restrict__ rkh, const unsigned short* __restrict__ rkl,
    const unsigned short* __restrict__ rvt, float* __restrict__ out)
{
    __shared__ __align__(16) unsigned short qrel_u[16 * NP2_];  // 64 KB; P (16 x PS_) aliased after scores
    __shared__ __align__(16) float Sf[16 * SS_];                // 65.8 KB; hist aliased after softmax
    __shared__ __align__(16) float red[8][16][20];              // 10 KB cross-wave O reduce
    __shared__ float inv_l[16];

    const int t    = threadIdx.x;
    const int w    = t >> 6;
    const int lane = t & 63;
    const int mrow = lane & 15;     // A-row (M) / B-col (N) / C-col
    const int grp  = lane >> 4;     // k-chunk group; C rows = grp*4 + r
    const int i0   = blockIdx.x * 16;
    const int h    = blockIdx.y;
    const int b    = blockIdx.z;
    const size_t bh = (size_t)b * H_ + h;

    const unsigned short* qhp = qh + bh * (size_t)(L_ * DH_);
    const unsigned short* qlp = ql + bh * (size_t)(L_ * DH_);
    const unsigned short* khp = kh + bh * (size_t)(L_ * DH_);
    const unsigned short* klp = kl + bh * (size_t)(L_ * DH_);
    const unsigned short* vtp = vt + bh * (size_t)(DH_ * L_);

    // Q A-fragments (hoisted once): A[m=mrow][k = s*32 + grp*8 + 0..7]
    bf16x8 qAh[2], qAl[2];
#pragma unroll
    for (int s = 0; s < 2; ++s) {
        const size_t off = (size_t)(i0 + mrow) * DH_ + s * 32 + grp * 8;
        qAh[s] = *(const bf16x8*)(qhp + off);
        qAl[s] = *(const bf16x8*)(qlp + off);
    }

    // ---- Phase 1: Qrel (16 p-tiles per wave) ----
#pragma unroll 2
    for (int tt = 0; tt < 16; ++tt) {
        const int ptile = w * 16 + tt;
        const int pcol  = ptile * 16 + mrow;               // B-col (p), row 2047 is zero pad
        const size_t boff = (size_t)pcol * DH_ + grp * 8;
        bf16x8 Bh0 = *(const bf16x8*)(rkh + boff);
        bf16x8 Bh1 = *(const bf16x8*)(rkh + boff + 32);
        bf16x8 Bl0 = *(const bf16x8*)(rkl + boff);
        bf16x8 Bl1 = *(const bf16x8*)(rkl + boff + 32);
        f32x4 c = {0.f, 0.f, 0.f, 0.f};
        c = __builtin_amdgcn_mfma_f32_16x16x32_bf16(qAh[0], Bh0, c, 0, 0, 0);
        c = __builtin_amdgcn_mfma_f32_16x16x32_bf16(qAh[1], Bh1, c, 0, 0, 0);
        c = __builtin_amdgcn_mfma_f32_16x16x32_bf16(qAh[0], Bl0, c, 0, 0, 0);
        c = __builtin_amdgcn_mfma_f32_16x16x32_bf16(qAh[1], Bl1, c, 0, 0, 0);
        c = __builtin_amdgcn_mfma_f32_16x16x32_bf16(qAl[0], Bh0, c, 0, 0, 0);
        c = __builtin_amdgcn_mfma_f32_16x16x32_bf16(qAl[1], Bh1, c, 0, 0, 0);
#pragma unroll
        for (int r = 0; r < 4; ++r)
            qrel_u[(grp * 4 + r) * NP2_ + pcol] = f2bf(c[r]);
    }
    __syncthreads();

    // ---- Phase 2: content scores + rel add (8 j-tiles per wave) ----
#pragma unroll 2
    for (int tt = 0; tt < 8; ++tt) {
        const int jcol = (w * 8 + tt) * 16 + mrow;
        const size_t boff = (size_t)jcol * DH_ + grp * 8;
        bf16x8 Bh0 = *(const bf16x8*)(khp + boff);
        bf16x8 Bh1 = *(const bf16x8*)(khp + boff + 32);
        bf16x8 Bl0 = *(const bf16x8*)(klp + boff);
        bf16x8 Bl1 = *(const bf16x8*)(klp + boff + 32);
        f32x4 c = {0.f, 0.f, 0.f, 0.f};
        c = __builtin_amdgcn_mfma_f32_16x16x32_bf16(qAh[0], Bh0, c, 0, 0, 0);
        c = __builtin_amdgcn_mfma_f32_16x16x32_bf16(qAh[1], Bh1, c, 0, 0, 0);
        c = __builtin_amdgcn_mfma_f32_16x16x32_bf16(qAh[0], Bl0, c, 0, 0, 0);
        c = __builtin_amdgcn_mfma_f32_16x16x32_bf16(qAh[1], Bl1, c, 0, 0, 0);
        c = __builtin_amdgcn_mfma_f32_16x16x32_bf16(qAl[0], Bh0, c, 0, 0, 0);
        c = __builtin_amdgcn_mfma_f32_16x16x32_bf16(qAl[1], Bh1, c, 0, 0, 0);
#pragma unroll
        for (int r = 0; r < 4; ++r) {
            const int rr = grp * 4 + r;
            const int pidx = ridx[(size_t)(i0 + rr) * L_ + jcol];
            Sf[rr * SS_ + jcol] = (c[r] + bf2f(qrel_u[rr * NP2_ + pidx])) * SCALE_;
        }
    }
    __syncthreads();

    // ---- Phase 3: softmax rows 2w, 2w+1; P (bf16, unnormalized) aliases qrel ----
    unsigned short* Pu = qrel_u;
#pragma unroll
    for (int rloc = 0; rloc < 2; ++rloc) {
        const int row = w * 2 + rloc;
        float m = -1e30f;
#pragma unroll
        for (int c = 0; c < 16; ++c) m = fmaxf(m, Sf[row * SS_ + c * 64 + lane]);
#pragma unroll
        for (int off = 32; off >= 1; off >>= 1) m = fmaxf(m, __shfl_xor(m, off));
        float sum = 0.f;
#pragma unroll
        for (int c = 0; c < 16; ++c) {
            const float e = __expf(Sf[row * SS_ + c * 64 + lane] - m);
            Pu[row * PS_ + c * 64 + lane] = f2bf(e);
            sum += e;
        }
#pragma unroll
        for (int off = 32; off >= 1; off >>= 1) sum += __shfl_xor(sum, off);
        if (lane == 0) inv_l[row] = 1.0f / sum;
    }
    __syncthreads();

    // ---- Phase 4: O1 = P @ V, wave task (n, khalf) ----
    const int n = w & 3;
    const int khalf = w >> 2;
    f32x4 acc = {0.f, 0.f, 0.f, 0.f};
    {
        const unsigned short* vcol = vtp + (size_t)(n * 16 + mrow) * L_;
#pragma unroll 4
        for (int s = 0; s < 16; ++s) {
            const int kb = khalf * 512 + s * 32;
            bf16x8 a = *(const bf16x8*)(Pu + mrow * PS_ + kb + grp * 8);
            bf16x8 bf = *(const bf16x8*)(vcol + kb + grp * 8);
            acc = __builtin_amdgcn_mfma_f32_16x16x32_bf16(a, bf, acc, 0, 0, 0);
        }
    }

    // ---- Phase 5: hist passes (hist f32 aliases Sf) ----
    float* hist = Sf;
    for (int pass = 0; pass < 2; ++pass) {
        __syncthreads();                        // S dead / prev O2 done
        for (int z = t; z < 16 * 1024; z += 512)
            hist[(z >> 10) * SS_ + (z & 1023)] = 0.f;
        __syncthreads();
        // scatter own rows
#pragma unroll
        for (int rloc = 0; rloc < 2; ++rloc) {
            const int row = w * 2 + rloc;
            const int* idxr = ridx + (size_t)(i0 + row) * L_;
#pragma unroll
            for (int c = 0; c < 16; ++c) {
                const int j = c * 64 + lane;
                const int pidx = idxr[j];
                if ((pidx >> 10) == pass)
                    atomicAdd(&hist[row * SS_ + (pidx & 1023)], bf2f(Pu[row * PS_ + j]));
            }
        }
        __syncthreads();
        // O2 partial: A = hist rows (cvt f32->bf16), B = rv_t
        const unsigned short* rvcol = rvt + (size_t)(n * 16 + mrow) * NP2_ + pass * 1024;
#pragma unroll 2
        for (int s = 0; s < 16; ++s) {
            const int kb = khalf * 512 + s * 32;
            const f32x4* hp = (const f32x4*)&hist[mrow * SS_ + kb + grp * 8];
            f32x4 h0 = hp[0], h1 = hp[1];
            bf16x8 a;
#pragma unroll
            for (int e = 0; e < 4; ++e) { a[e] = (short)f2bf(h0[e]); a[e + 4] = (short)f2bf(h1[e]); }
            bf16x8 bf = *(const bf16x8*)(rvcol + kb + grp * 8);
            acc = __builtin_amdgcn_mfma_f32_16x16x32_bf16(a, bf, acc, 0, 0, 0);
        }
    }

    // ---- Phase 6: khalf reduce + store ----
    __syncthreads();
#pragma unroll
    for (int r = 0; r < 4; ++r) red[w][grp * 4 + r][mrow] = acc[r];
    __syncthreads();
    if (w < 4) {
#pragma unroll
        for (int r = 0; r < 4; ++r) {
            const int rr = grp * 4 + r;
            const float o = (red[w][rr][mrow] + red[w + 4][rr][mrow]) * inv_l[rr];
            out[((size_t)b * L_ + i0 + rr) * DM_ + h * DH_ + w * 16 + mrow] = o;
        }
    }
}

extern "C" void kernel_launch(void* const* d_in, const int* in_sizes, int n_in,
                              void* d_out, int out_size, void* d_ws, size_t ws_size,
                              hipStream_t stream)
{
    const float* x    = (const float*)d_in[0];
    const int*   ridx = (const int*)  d_in[1];
    const float* Wq   = (const float*)d_in[2];
    const float* Wk   = (const float*)d_in[3];
    const float* Wv   = (const float*)d_in[4];
    const float* Wo   = (const float*)d_in[5];
    const float* rk   = (const float*)d_in[6];
    const float* rv   = (const float*)d_in[7];
    float* out = (float*)d_out;

    const size_t NQ = (size_t)B_ * H_ * L_ * DH_;      // 8,388,608
    float* attn = (float*)d_ws;                        // NQ f32
    unsigned short* u = (unsigned short*)(attn + NQ);
    unsigned short* qh = u;            u += NQ;
    unsigned short* ql = u;            u += NQ;
    unsigned short* kh = u;            u += NQ;
    unsigned short* kl = u;            u += NQ;
    unsigned short* vt = u;            u += NQ;
    unsigned short* rkh = u;           u += (size_t)NP2_ * DH_;
    unsigned short* rkl = u;           u += (size_t)NP2_ * DH_;
    unsigned short* rvt = u;           u += (size_t)NP2_ * DH_;

    dim3 gthr(256);
    dim3 ggrid((B_ * L_) / 64, DM_ / 64);   // (128, 16)

    prep_rel<<<dim3((NP2_ * DH_) / 256), gthr, 0, stream>>>(rk, rv, rkh, rkl, rvt);
    proj_gemm<0><<<ggrid, gthr, 0, stream>>>(x, Wq, nullptr, qh, ql);
    proj_gemm<0><<<ggrid, gthr, 0, stream>>>(x, Wk, nullptr, kh, kl);
    proj_gemm<2><<<ggrid, gthr, 0, stream>>>(x, Wv, nullptr, vt, nullptr);

    shaw_attn_mfma<<<dim3(L_ / 16, H_, B_), dim3(512), 0, stream>>>(
        qh, ql, kh, kl, vt, ridx, rkh, rkl, rvt, attn);

    proj_gemm<1><<<ggrid, gthr, 0, stream>>>(attn, Wo, out, nullptr, nullptr);
}

// Round 4
// 2404.516 us; speedup vs baseline: 2.3890x; 1.1839x over previous
//
#include <hip/hip_runtime.h>

#define B_ 8
#define H_ 16
#define L_ 1024
#define DH_ 64
#define DM_ 1024
#define NP_ 2047
#define NP2_ 2048
#define SCALE_ 0.125f

#define PS_ 1032   // P bf16 row stride
#define HS_ 516    // hist f32 row stride (4-pass, 512 + pad)

typedef __attribute__((ext_vector_type(8))) short bf16x8;
typedef __attribute__((ext_vector_type(4))) float f32x4;

__device__ __forceinline__ unsigned short f2bf(float x) {
    union { float f; unsigned int u; } v; v.f = x;
    return (unsigned short)((v.u + 0x7FFFu + ((v.u >> 16) & 1u)) >> 16);
}
__device__ __forceinline__ float bf2f(unsigned short b) {
    union { unsigned int u; float f; } v; v.u = ((unsigned int)b) << 16;
    return v.f;
}

// ---------------- projection GEMM: Y = X @ W^T (fp32 VALU core) ----------------
// MODE 0: head-split hi/lo bf16 (q, k); MODE 1: fp32 flat (Wo); MODE 2: head-split transposed bf16 (v)
template <int MODE>
__global__ __launch_bounds__(256) void proj_gemm(const float* __restrict__ X,
                                                 const float* __restrict__ W,
                                                 float* __restrict__ Yf,
                                                 unsigned short* __restrict__ Y0,
                                                 unsigned short* __restrict__ Y1)
{
    __shared__ __align__(16) float As[16][68];
    __shared__ __align__(16) float Bs[16][68];
    const int t   = threadIdx.x;
    const int tm  = t & 15;
    const int tn  = t >> 4;
    const int row0 = blockIdx.x * 64;
    const int col0 = blockIdx.y * 64;
    const int lr = t >> 2;
    const int lc = (t & 3) * 4;

    float acc[4][4];
#pragma unroll
    for (int i = 0; i < 4; ++i)
#pragma unroll
        for (int j = 0; j < 4; ++j) acc[i][j] = 0.f;

    for (int k0 = 0; k0 < DM_; k0 += 16) {
        float4 av = *(const float4*)(X + (size_t)(row0 + lr) * DM_ + k0 + lc);
        float4 wv = *(const float4*)(W + (size_t)(col0 + lr) * DM_ + k0 + lc);
        __syncthreads();
        As[lc + 0][lr] = av.x; As[lc + 1][lr] = av.y;
        As[lc + 2][lr] = av.z; As[lc + 3][lr] = av.w;
        Bs[lc + 0][lr] = wv.x; Bs[lc + 1][lr] = wv.y;
        Bs[lc + 2][lr] = wv.z; Bs[lc + 3][lr] = wv.w;
        __syncthreads();
#pragma unroll
        for (int kk = 0; kk < 16; ++kk) {
            float4 a  = *(const float4*)&As[kk][tm * 4];
            float4 w4 = *(const float4*)&Bs[kk][tn * 4];
            acc[0][0] = fmaf(a.x, w4.x, acc[0][0]);
            acc[0][1] = fmaf(a.x, w4.y, acc[0][1]);
            acc[0][2] = fmaf(a.x, w4.z, acc[0][2]);
            acc[0][3] = fmaf(a.x, w4.w, acc[0][3]);
            acc[1][0] = fmaf(a.y, w4.x, acc[1][0]);
            acc[1][1] = fmaf(a.y, w4.y, acc[1][1]);
            acc[1][2] = fmaf(a.y, w4.z, acc[1][2]);
            acc[1][3] = fmaf(a.y, w4.w, acc[1][3]);
            acc[2][0] = fmaf(a.z, w4.x, acc[2][0]);
            acc[2][1] = fmaf(a.z, w4.y, acc[2][1]);
            acc[2][2] = fmaf(a.z, w4.z, acc[2][2]);
            acc[2][3] = fmaf(a.z, w4.w, acc[2][3]);
            acc[3][0] = fmaf(a.w, w4.x, acc[3][0]);
            acc[3][1] = fmaf(a.w, w4.y, acc[3][1]);
            acc[3][2] = fmaf(a.w, w4.z, acc[3][2]);
            acc[3][3] = fmaf(a.w, w4.w, acc[3][3]);
        }
    }

    const int h = blockIdx.y;
#pragma unroll
    for (int i = 0; i < 4; ++i) {
        const int row = row0 + tm * 4 + i;
        if (MODE == 1) {
            float4 r = make_float4(acc[i][0], acc[i][1], acc[i][2], acc[i][3]);
            *(float4*)(Yf + (size_t)row * DM_ + col0 + tn * 4) = r;
        } else {
            const int bb = row >> 10;
            const int l  = row & 1023;
            if (MODE == 0) {
                ushort4 hi4, lo4;
                unsigned short* hp = (unsigned short*)&hi4;
                unsigned short* lp = (unsigned short*)&lo4;
#pragma unroll
                for (int j = 0; j < 4; ++j) {
                    unsigned short hb = f2bf(acc[i][j]);
                    hp[j] = hb;
                    lp[j] = f2bf(acc[i][j] - bf2f(hb));
                }
                const size_t base = (((size_t)bb * H_ + h) * L_ + l) * DH_ + tn * 4;
                *(ushort4*)(Y0 + base) = hi4;
                *(ushort4*)(Y1 + base) = lo4;
            } else {  // MODE 2: transposed bf16
#pragma unroll
                for (int j = 0; j < 4; ++j) {
                    const int d = tn * 4 + j;
                    Y0[(((size_t)bb * H_ + h) * DH_ + d) * L_ + l] = f2bf(acc[i][j]);
                }
            }
        }
    }
}

// ---------------- rel_k bf16 + rel_v transpose prep ----------------
__global__ __launch_bounds__(256) void prep_rel(const float* __restrict__ rk,
                                                const float* __restrict__ rv,
                                                unsigned short* __restrict__ rk_hi,
                                                unsigned short* __restrict__ rv_t)
{
    const int idx = blockIdx.x * 256 + threadIdx.x;   // 0 .. 2048*64-1
    const int p = idx >> 6;
    const int d = idx & 63;
    float xk = (p < NP_) ? rk[(size_t)p * DH_ + d] : 0.f;
    rk_hi[idx] = f2bf(xk);
    float xv = (p < NP_) ? rv[(size_t)p * DH_ + d] : 0.f;
    rv_t[(size_t)d * NP2_ + p] = f2bf(xv);
}

// ---------------- MFMA Shaw attention v2: 16 Q-rows per block, 8 waves, 2 blocks/CU ----------------
// Phase 1: qrel int8 (x128) [p][16] in LDS        (pure-bf16 MFMA, 2/tile)
// Phase 2: scores in REGISTERS (sc[8][4])          (split-bf16 QK^T, 6 MFMA/tile)
// Phase 3: softmax via reg + 16-lane shfl + tiny LDS cross-wave reduce; P bf16 -> aliases qrel
// Phase 4: O1 = P @ V (wave task (n, khalf)); build packed (pidx|pbf16) scatter cache
// Phase 5: 4 passes x {zero hist[16][516], scatter (LDS f32 atomics), O2 += hist @ rel_v}
// Phase 6: khalf reduce (red aliases hist), 1/sum from psum, store
__global__ __launch_bounds__(512, 4) void shaw_attn_mfma(
    const unsigned short* __restrict__ qh, const unsigned short* __restrict__ ql,
    const unsigned short* __restrict__ kh, const unsigned short* __restrict__ kl,
    const unsigned short* __restrict__ vt, const int* __restrict__ ridx,
    const unsigned short* __restrict__ rkh, const unsigned short* __restrict__ rvt,
    float* __restrict__ out)
{
    __shared__ __align__(16) unsigned char regionA[16 * PS_ * 2];  // 33,024 B: qrel8 -> P
    __shared__ __align__(16) unsigned char regionB[16 * HS_ * 4];  // 33,024 B: hist -> red
    __shared__ float pmax[16][8];
    __shared__ float psum[16][8];

    char*           qrel8 = (char*)regionA;              // [p][16] : p*16 + rr
    unsigned short* Pu    = (unsigned short*)regionA;    // [16][PS_]
    float*          hist  = (float*)regionB;             // [16][HS_]
    float*          red   = (float*)regionB;             // [8][16][20]

    const int t    = threadIdx.x;
    const int w    = t >> 6;
    const int lane = t & 63;
    const int mrow = lane & 15;
    const int grp  = lane >> 4;
    const int i0   = blockIdx.x * 16;
    const int h    = blockIdx.y;
    const int b    = blockIdx.z;
    const size_t bh = (size_t)b * H_ + h;

    const unsigned short* qhp = qh + bh * (size_t)(L_ * DH_);
    const unsigned short* qlp = ql + bh * (size_t)(L_ * DH_);
    const unsigned short* khp = kh + bh * (size_t)(L_ * DH_);
    const unsigned short* klp = kl + bh * (size_t)(L_ * DH_);
    const unsigned short* vtp = vt + bh * (size_t)(DH_ * L_);

    // Q A-fragments
    bf16x8 qAh[2], qAl[2];
#pragma unroll
    for (int s = 0; s < 2; ++s) {
        const size_t off = (size_t)(i0 + mrow) * DH_ + s * 32 + grp * 8;
        qAh[s] = *(const bf16x8*)(qhp + off);
        qAl[s] = *(const bf16x8*)(qlp + off);
    }

    // ---- Phase 1: qrel int8 ----
#pragma unroll 4
    for (int tt = 0; tt < 16; ++tt) {
        const int pcol = (w * 16 + tt) * 16 + mrow;
        const size_t boff = (size_t)pcol * DH_ + grp * 8;
        bf16x8 Bh0 = *(const bf16x8*)(rkh + boff);
        bf16x8 Bh1 = *(const bf16x8*)(rkh + boff + 32);
        f32x4 c = {0.f, 0.f, 0.f, 0.f};
        c = __builtin_amdgcn_mfma_f32_16x16x32_bf16(qAh[0], Bh0, c, 0, 0, 0);
        c = __builtin_amdgcn_mfma_f32_16x16x32_bf16(qAh[1], Bh1, c, 0, 0, 0);
        unsigned int pk = 0;
#pragma unroll
        for (int r = 0; r < 4; ++r) {
            int qi = (int)rintf(c[r] * 128.f);
            qi = qi > 127 ? 127 : (qi < -127 ? -127 : qi);
            pk |= ((unsigned int)(qi & 0xff)) << (8 * r);
        }
        *(unsigned int*)(qrel8 + pcol * 16 + grp * 4) = pk;
    }
    __syncthreads();   // qrel ready

    // ---- Phase 2: scores in registers ----
    float sc[8][4];
#pragma unroll 2
    for (int tt = 0; tt < 8; ++tt) {
        const int jcol = (w * 8 + tt) * 16 + mrow;
        const size_t boff = (size_t)jcol * DH_ + grp * 8;
        bf16x8 Bh0 = *(const bf16x8*)(khp + boff);
        bf16x8 Bh1 = *(const bf16x8*)(khp + boff + 32);
        bf16x8 Bl0 = *(const bf16x8*)(klp + boff);
        bf16x8 Bl1 = *(const bf16x8*)(klp + boff + 32);
        f32x4 c = {0.f, 0.f, 0.f, 0.f};
        c = __builtin_amdgcn_mfma_f32_16x16x32_bf16(qAh[0], Bh0, c, 0, 0, 0);
        c = __builtin_amdgcn_mfma_f32_16x16x32_bf16(qAh[1], Bh1, c, 0, 0, 0);
        c = __builtin_amdgcn_mfma_f32_16x16x32_bf16(qAh[0], Bl0, c, 0, 0, 0);
        c = __builtin_amdgcn_mfma_f32_16x16x32_bf16(qAh[1], Bl1, c, 0, 0, 0);
        c = __builtin_amdgcn_mfma_f32_16x16x32_bf16(qAl[0], Bh0, c, 0, 0, 0);
        c = __builtin_amdgcn_mfma_f32_16x16x32_bf16(qAl[1], Bh1, c, 0, 0, 0);
#pragma unroll
        for (int r = 0; r < 4; ++r) {
            const int rr = grp * 4 + r;
            const int pidx = ridx[(size_t)(i0 + rr) * L_ + jcol];
            const float rel = (float)qrel8[pidx * 16 + grp * 4 + r];
            sc[tt][r] = fmaf(rel, SCALE_ / 128.f, c[r] * SCALE_);
        }
    }

    // ---- Phase 3: softmax ----
    float mx[4];
#pragma unroll
    for (int r = 0; r < 4; ++r) {
        float m = sc[0][r];
#pragma unroll
        for (int tt = 1; tt < 8; ++tt) m = fmaxf(m, sc[tt][r]);
#pragma unroll
        for (int off = 1; off < 16; off <<= 1) m = fmaxf(m, __shfl_xor(m, off));
        mx[r] = m;
    }
    {
        const float wv0 = (mrow == 0) ? mx[0] : (mrow == 1) ? mx[1] : (mrow == 2) ? mx[2] : mx[3];
        if (mrow < 4) pmax[grp * 4 + mrow][w] = wv0;
    }
    __syncthreads();   // qrel dead (all gathers done) + pmax ready

    float gm[4];
#pragma unroll
    for (int r = 0; r < 4; ++r) {
        const int rr = grp * 4 + r;
        float m = pmax[rr][0];
#pragma unroll
        for (int u = 1; u < 8; ++u) m = fmaxf(m, pmax[rr][u]);
        gm[r] = m;
    }
    float sm[4];
#pragma unroll
    for (int r = 0; r < 4; ++r) {
        const int rr = grp * 4 + r;
        float s = 0.f;
#pragma unroll
        for (int tt = 0; tt < 8; ++tt) {
            const float e = __expf(sc[tt][r] - gm[r]);
            s += e;
            Pu[rr * PS_ + (w * 8 + tt) * 16 + mrow] = f2bf(e);   // writes into dead qrel
        }
#pragma unroll
        for (int off = 1; off < 16; off <<= 1) s += __shfl_xor(s, off);
        sm[r] = s;
    }
    {
        const float sv0 = (mrow == 0) ? sm[0] : (mrow == 1) ? sm[1] : (mrow == 2) ? sm[2] : sm[3];
        if (mrow < 4) psum[grp * 4 + mrow][w] = sv0;
    }
    __syncthreads();   // P + psum ready

    // ---- Phase 4: O1 = P @ V ----
    const int n = w & 3;
    const int khalf = w >> 2;
    f32x4 acc = {0.f, 0.f, 0.f, 0.f};
    {
        const unsigned short* vcol = vtp + (size_t)(n * 16 + mrow) * L_;
#pragma unroll 4
        for (int s = 0; s < 16; ++s) {
            const int kb = khalf * 512 + s * 32;
            bf16x8 a = *(const bf16x8*)(Pu + mrow * PS_ + kb + grp * 8);
            bf16x8 bb = *(const bf16x8*)(vcol + kb + grp * 8);
            acc = __builtin_amdgcn_mfma_f32_16x16x32_bf16(a, bb, acc, 0, 0, 0);
        }
    }

    // ---- build packed scatter cache: rows 2w, 2w+1 ----
    unsigned int cache[32];
    {
        const int* idx0 = ridx + (size_t)(i0 + 2 * w) * L_;
        const int* idx1 = idx0 + L_;
#pragma unroll
        for (int c = 0; c < 16; ++c) {
            const int j = c * 64 + lane;
            cache[c]      = (((unsigned int)idx0[j]) << 16) | (unsigned int)Pu[(2 * w) * PS_ + j];
            cache[c + 16] = (((unsigned int)idx1[j]) << 16) | (unsigned int)Pu[(2 * w + 1) * PS_ + j];
        }
    }

    // ---- Phase 5: 4 hist passes ----
    for (int pass = 0; pass < 4; ++pass) {
        __syncthreads();                       // previous hist readers done
        for (int z = t; z < 16 * HS_; z += 512) hist[z] = 0.f;
        __syncthreads();
#pragma unroll
        for (int e = 0; e < 32; ++e) {
            const unsigned int pk = cache[e];
            const int pidx = (int)(pk >> 16);
            if ((pidx >> 9) == pass) {
                const int row = 2 * w + (e >> 4);
                atomicAdd(&hist[row * HS_ + (pidx & 511)], bf2f((unsigned short)(pk & 0xffffu)));
            }
        }
        __syncthreads();
        const unsigned short* rvcol = rvt + (size_t)(n * 16 + mrow) * NP2_ + pass * 512;
#pragma unroll
        for (int s = 0; s < 8; ++s) {
            const int kb = khalf * 256 + s * 32;
            const f32x4* hp = (const f32x4*)&hist[mrow * HS_ + kb + grp * 8];
            f32x4 h0 = hp[0], h1 = hp[1];
            bf16x8 a;
#pragma unroll
            for (int e = 0; e < 4; ++e) { a[e] = (short)f2bf(h0[e]); a[e + 4] = (short)f2bf(h1[e]); }
            bf16x8 bb = *(const bf16x8*)(rvcol + kb + grp * 8);
            acc = __builtin_amdgcn_mfma_f32_16x16x32_bf16(a, bb, acc, 0, 0, 0);
        }
    }

    // ---- Phase 6: khalf reduce + normalize + store ----
    __syncthreads();                           // hist dead -> red alias safe
#pragma unroll
    for (int r = 0; r < 4; ++r) red[w * 320 + (grp * 4 + r) * 20 + mrow] = acc[r];
    __syncthreads();
    if (w < 4) {
#pragma unroll
        for (int r = 0; r < 4; ++r) {
            const int rr = grp * 4 + r;
            float o = red[w * 320 + rr * 20 + mrow] + red[(w + 4) * 320 + rr * 20 + mrow];
            float ssum = 0.f;
#pragma unroll
            for (int u = 0; u < 8; ++u) ssum += psum[rr][u];
            out[((size_t)b * L_ + i0 + rr) * DM_ + h * DH_ + w * 16 + mrow] = o / ssum;
        }
    }
}

extern "C" void kernel_launch(void* const* d_in, const int* in_sizes, int n_in,
                              void* d_out, int out_size, void* d_ws, size_t ws_size,
                              hipStream_t stream)
{
    const float* x    = (const float*)d_in[0];
    const int*   ridx = (const int*)  d_in[1];
    const float* Wq   = (const float*)d_in[2];
    const float* Wk   = (const float*)d_in[3];
    const float* Wv   = (const float*)d_in[4];
    const float* Wo   = (const float*)d_in[5];
    const float* rk   = (const float*)d_in[6];
    const float* rv   = (const float*)d_in[7];
    float* out = (float*)d_out;

    const size_t NQ = (size_t)B_ * H_ * L_ * DH_;      // 8,388,608
    float* attn = (float*)d_ws;                        // NQ f32
    unsigned short* u = (unsigned short*)(attn + NQ);
    unsigned short* qh = u;            u += NQ;
    unsigned short* ql = u;            u += NQ;
    unsigned short* kh = u;            u += NQ;
    unsigned short* kl = u;            u += NQ;
    unsigned short* vt = u;            u += NQ;
    unsigned short* rkh = u;           u += (size_t)NP2_ * DH_;
    unsigned short* rvt = u;           u += (size_t)NP2_ * DH_;

    dim3 gthr(256);
    dim3 ggrid((B_ * L_) / 64, DM_ / 64);   // (128, 16)

    prep_rel<<<dim3((NP2_ * DH_) / 256), gthr, 0, stream>>>(rk, rv, rkh, rvt);
    proj_gemm<0><<<ggrid, gthr, 0, stream>>>(x, Wq, nullptr, qh, ql);
    proj_gemm<0><<<ggrid, gthr, 0, stream>>>(x, Wk, nullptr, kh, kl);
    proj_gemm<2><<<ggrid, gthr, 0, stream>>>(x, Wv, nullptr, vt, nullptr);

    shaw_attn_mfma<<<dim3(L_ / 16, H_, B_), dim3(512), 0, stream>>>(
        qh, ql, kh, kl, vt, ridx, rkh, rvt, attn);

    proj_gemm<1><<<ggrid, gthr, 0, stream>>>(attn, Wo, out, nullptr, nullptr);
}